// Round 1
// baseline (180.988 us; speedup 1.0000x reference)
//
#include <hip/hip_runtime.h>

#define B     4096
#define KNB   64
#define D     128
#define NREL  32
#define EPS   1e-5f

// ---------------------------------------------------------------------------
// Generic 128-wide row GEMM: out[r][c] = f( in[r]·W[:,c] + bias[c] )
// mode 0: out = acc
// mode 1: out = add + lrelu(acc)
// nrows must be a multiple of 32 (all call sites are: 200000, 8192).
// Block: 256 threads; each block does 32 rows x 128 cols, 4x4 register tile.
// ---------------------------------------------------------------------------
__global__ __launch_bounds__(256) void gemm128(
    const float* __restrict__ in, const float* __restrict__ W,
    const float* __restrict__ bias, const float* __restrict__ add,
    float* __restrict__ out, int mode)
{
    __shared__ float Wl[128 * 128];   // 64 KB
    __shared__ float inl[32 * 128];   // 16 KB
    const int t = threadIdx.x;

    { // stage W (16384 f32 = 4096 float4, 16 per thread)
        const float4* W4 = (const float4*)W;
        float4* Wl4 = (float4*)Wl;
        #pragma unroll
        for (int m = 0; m < 16; ++m) Wl4[t + m * 256] = W4[t + m * 256];
    }
    const size_t row0 = (size_t)blockIdx.x * 32;
    { // stage input tile (32x128 = 1024 float4, 4 per thread)
        const float4* in4 = (const float4*)(in + row0 * D);
        float4* inl4 = (float4*)inl;
        #pragma unroll
        for (int m = 0; m < 4; ++m) inl4[t + m * 256] = in4[t + m * 256];
    }
    __syncthreads();

    const int cq = t & 31;   // col quad 0..31
    const int rq = t >> 5;   // row quad 0..7
    const int c0 = cq * 4;
    const int r0 = rq * 4;

    float acc[4][4];
    {
        float4 bv = *(const float4*)&bias[c0];
        #pragma unroll
        for (int i = 0; i < 4; ++i) {
            acc[i][0] = bv.x; acc[i][1] = bv.y; acc[i][2] = bv.z; acc[i][3] = bv.w;
        }
    }

    for (int k = 0; k < 128; k += 4) {
        float4 a[4], w[4];
        #pragma unroll
        for (int i = 0; i < 4; ++i) a[i] = *(const float4*)&inl[(r0 + i) * D + k];
        #pragma unroll
        for (int kk = 0; kk < 4; ++kk) w[kk] = *(const float4*)&Wl[(k + kk) * D + c0];
        #pragma unroll
        for (int i = 0; i < 4; ++i) {
            const float* ai = (const float*)&a[i];
            #pragma unroll
            for (int kk = 0; kk < 4; ++kk) {
                acc[i][0] = fmaf(ai[kk], w[kk].x, acc[i][0]);
                acc[i][1] = fmaf(ai[kk], w[kk].y, acc[i][1]);
                acc[i][2] = fmaf(ai[kk], w[kk].z, acc[i][2]);
                acc[i][3] = fmaf(ai[kk], w[kk].w, acc[i][3]);
            }
        }
    }

    #pragma unroll
    for (int i = 0; i < 4; ++i) {
        const size_t r = row0 + r0 + i;
        float4 o = make_float4(acc[i][0], acc[i][1], acc[i][2], acc[i][3]);
        if (mode == 1) {
            float4 ad = *(const float4*)&add[r * D + c0];
            o.x = ad.x + (o.x >= 0.f ? o.x : 0.2f * o.x);
            o.y = ad.y + (o.y >= 0.f ? o.y : 0.2f * o.y);
            o.z = ad.z + (o.z >= 0.f ? o.z : 0.2f * o.z);
            o.w = ad.w + (o.w >= 0.f ? o.w : 0.2f * o.w);
        }
        *(float4*)&out[r * D + c0] = o;
    }
}

// ---------------------------------------------------------------------------
// h0[j][b][:] = bn(entity_embs[idx_j[b]]); j=0 -> i, j=1 -> u
// one thread per float4: 2*B*32 threads
// ---------------------------------------------------------------------------
__global__ __launch_bounds__(256) void bn_gather(
    const int* __restrict__ i_idx, const int* __restrict__ u_idx,
    const float* __restrict__ embs,
    const float* __restrict__ gamma, const float* __restrict__ beta,
    const float* __restrict__ mean,  const float* __restrict__ var,
    float* __restrict__ h0)
{
    const int tid = blockIdx.x * 256 + threadIdx.x;   // 0 .. 2*B*32-1
    const int d4 = tid & 31;
    const int b  = (tid >> 5) & (B - 1);
    const int j  = tid >> 17;
    const int idx = j ? u_idx[b] : i_idx[b];

    const int d0 = d4 * 4;
    float4 x = *(const float4*)&embs[(size_t)idx * D + d0];
    float4 m = *(const float4*)&mean[d0];
    float4 v = *(const float4*)&var[d0];
    float4 g = *(const float4*)&gamma[d0];
    float4 bt = *(const float4*)&beta[d0];

    float4 o;
    o.x = (x.x - m.x) * g.x * rsqrtf(v.x + EPS) + bt.x;
    o.y = (x.y - m.y) * g.y * rsqrtf(v.y + EPS) + bt.y;
    o.z = (x.z - m.z) * g.z * rsqrtf(v.z + EPS) + bt.z;
    o.w = (x.w - m.w) * g.w * rsqrtf(v.w + EPS) + bt.w;

    *(float4*)&h0[(size_t)tid * 4] = o;   // tid*4 == (j*B + b)*128 + d0
}

// ---------------------------------------------------------------------------
// Per (j,b): build 32x128 tanh table, accumulate FM sums over K=64 neighbors,
// write g = h0 + (s*s - sum(v*v)).
// ---------------------------------------------------------------------------
__global__ __launch_bounds__(256) void aggregate(
    const int* __restrict__ i_idx, const int* __restrict__ u_idx,
    const int* __restrict__ adj_e, const int* __restrict__ adj_r,
    const float* __restrict__ Etr, const float* __restrict__ rel_embs,
    const float* __restrict__ hW,  const float* __restrict__ h0,
    float* __restrict__ g_out)
{
    __shared__ float hw_s[D];
    __shared__ float tt[NREL * D];    // 16 KB
    __shared__ int ents[KNB];
    __shared__ int rels[KNB];
    __shared__ float ps[2][D];
    __shared__ float pq[2][D];

    const int t = threadIdx.x;
    const int b = blockIdx.x & (B - 1);
    const int j = blockIdx.x >> 12;
    const size_t rowbase = ((size_t)j * B + b) * D;
    const int idx = j ? u_idx[b] : i_idx[b];

    if (t < D) hw_s[t] = hW[rowbase + t];
    if (t >= 128 && t < 128 + KNB) {
        const int k = t - 128;
        ents[k] = adj_e[(size_t)idx * KNB + k];
        rels[k] = adj_r[(size_t)idx * KNB + k];
    }
    __syncthreads();

    for (int m = t; m < NREL * D; m += 256)
        tt[m] = tanhf(hw_s[m & (D - 1)] + rel_embs[m]);
    __syncthreads();

    const int grp = t >> 7;
    const int d = t & (D - 1);
    float s = 0.f, q = 0.f;
    #pragma unroll 4
    for (int k = grp; k < KNB; k += 2) {
        const float v = Etr[(size_t)ents[k] * D + d] * tt[rels[k] * D + d];
        s += v;
        q = fmaf(v, v, q);
    }
    ps[grp][d] = s;
    pq[grp][d] = q;
    __syncthreads();

    if (t < D) {
        const float ss = ps[0][t] + ps[1][t];
        const float qq = pq[0][t] + pq[1][t];
        const float Nh = ss * ss - qq;
        g_out[rowbase + t] = h0[rowbase + t] + Nh;
    }
}

// ---------------------------------------------------------------------------
// out[b] = u_e[b]·wl[0:128] + h[b]·wl[128:256] + wl_b ; one wave per b
// ---------------------------------------------------------------------------
__global__ __launch_bounds__(256) void final_dot(
    const float* __restrict__ hfin, const float* __restrict__ wl_w,
    const float* __restrict__ wl_b, float* __restrict__ out)
{
    const int t = threadIdx.x;
    const int w = t >> 6;
    const int lane = t & 63;
    const int b = blockIdx.x * 4 + w;

    const float* hu = hfin + ((size_t)B + b) * D;  // j=1 : u_e
    const float* hh = hfin + (size_t)b * D;        // j=0 : h

    float v = hu[lane]      * wl_w[lane]
            + hu[lane + 64] * wl_w[lane + 64]
            + hh[lane]      * wl_w[128 + lane]
            + hh[lane + 64] * wl_w[192 + lane];
    #pragma unroll
    for (int off = 32; off; off >>= 1) v += __shfl_xor(v, off);
    if (lane == 0) out[b] = v + wl_b[0];
}

extern "C" void kernel_launch(void* const* d_in, const int* in_sizes, int n_in,
                              void* d_out, int out_size, void* d_ws, size_t ws_size,
                              hipStream_t stream) {
    const int*   u        = (const int*)d_in[0];
    const int*   ii       = (const int*)d_in[1];
    const int*   adj_e    = (const int*)d_in[2];
    const int*   adj_r    = (const int*)d_in[3];
    const float* embs     = (const float*)d_in[4];
    const float* rel_embs = (const float*)d_in[5];
    const float* gamma    = (const float*)d_in[6];
    const float* beta     = (const float*)d_in[7];
    const float* mean     = (const float*)d_in[8];
    const float* var      = (const float*)d_in[9];
    const float* Wr1_w    = (const float*)d_in[10];
    const float* Wr1_b    = (const float*)d_in[11];
    const float* W1_w     = (const float*)d_in[12];
    const float* W1_b     = (const float*)d_in[13];
    const float* wl_w     = (const float*)d_in[14];
    const float* wl_b     = (const float*)d_in[15];
    float* out = (float*)d_out;
    float* ws  = (float*)d_ws;

    const int n_ent = in_sizes[2] / KNB;    // 200000

    float* Etr  = ws;                            // [n_ent, 128]  102.4 MB
    float* h0   = Etr  + (size_t)n_ent * D;      // [2, B, 128]
    float* hWb  = h0   + (size_t)2 * B * D;      // [2, B, 128]
    float* gb   = hWb  + (size_t)2 * B * D;      // [2, B, 128]
    float* hfin = gb   + (size_t)2 * B * D;      // [2, B, 128]

    // 1. E_tr = entity_embs @ Wr1_w + Wr1_b   (shared by both layer calls)
    gemm128<<<n_ent / 32, 256, 0, stream>>>(embs, Wr1_w, Wr1_b, nullptr, Etr, 0);
    // 2. h0 = bn(entity_embs[{i,u}])
    bn_gather<<<(2 * B * 32) / 256, 256, 0, stream>>>(ii, u, embs, gamma, beta, mean, var, h0);
    // 3. hW = h0 @ Wr1_w + Wr1_b
    gemm128<<<(2 * B) / 32, 256, 0, stream>>>(h0, Wr1_w, Wr1_b, nullptr, hWb, 0);
    // 4. FM aggregation -> g = h0 + Nh
    aggregate<<<2 * B, 256, 0, stream>>>(ii, u, adj_e, adj_r, Etr, rel_embs, hWb, h0, gb);
    // 5. hfin = h0 + lrelu(g @ W1_w + W1_b)
    gemm128<<<(2 * B) / 32, 256, 0, stream>>>(gb, W1_w, W1_b, h0, hfin, 1);
    // 6. out = [u_e, h] @ wl_w + wl_b
    final_dot<<<B / 4, 256, 0, stream>>>(hfin, wl_w, wl_b, out);
}

// Round 2
// 118.399 us; speedup vs baseline: 1.5286x; 1.5286x over previous
//
#include <hip/hip_runtime.h>

#define B     4096
#define KNB   64
#define D     128
#define NREL  32
#define EPS   1e-5f

typedef __attribute__((ext_vector_type(8))) short bf16x8;
typedef __attribute__((ext_vector_type(4))) float f32x4;

__device__ inline unsigned short f2bf(float f) {
    unsigned u = __float_as_uint(f);
    return (unsigned short)((u + 0x7FFFu + ((u >> 16) & 1u)) >> 16);
}
__device__ inline float bf2f(unsigned short h) {
    return __uint_as_float((unsigned)h << 16);
}

// ---------------------------------------------------------------------------
// Wt[n][k] = bf16(W[k][n]) — one small block, runs once per launch
// ---------------------------------------------------------------------------
__global__ __launch_bounds__(256) void wt_prep(
    const float* __restrict__ W, unsigned short* __restrict__ Wt)
{
    const int t = threadIdx.x;
    #pragma unroll
    for (int m = 0; m < 64; ++m) {
        const int idx = m * 256 + t;
        const int k = idx >> 7, n = idx & 127;
        Wt[n * D + k] = f2bf(W[idx]);
    }
}

// ---------------------------------------------------------------------------
// Etr = bf16( in(f32) @ W + bias ), via 16x16x32 bf16 MFMA.
// Block: 256 thr (4 waves), tile 64 rows x 128 cols. Wave w: rows 16w..16w+15.
// LDS: A 64x128 bf16 (16KB) + Wt 128x128 bf16 (32KB), both XOR-swizzled
// ((row&7)<<4) to kill the 256B-row-stride bank conflict (guide §6 G4).
// ---------------------------------------------------------------------------
__global__ __launch_bounds__(256) void gemm_etr(
    const float* __restrict__ in, const unsigned short* __restrict__ Wt,
    const float* __restrict__ bias, unsigned short* __restrict__ outbf)
{
    __shared__ unsigned short Al[64 * 128];    // 16 KB
    __shared__ unsigned short Wl[128 * 128];   // 32 KB

    const int t = threadIdx.x;
    const size_t row0 = (size_t)blockIdx.x * 64;

    // stage Wt (bf16, pre-transposed [n][k]) -> LDS, swizzled. 2048 x 16B.
    {
        const float4* src = (const float4*)Wt;
        #pragma unroll
        for (int m = 0; m < 8; ++m) {
            const int c = m * 256 + t;
            const int n = c >> 4;                      // 16 chunks per 256B row
            float4 v = src[c];
            *(float4*)((char*)Wl + ((c * 16) ^ ((n & 7) << 4))) = v;
        }
    }
    // stage A rows (f32 -> bf16) -> LDS, swizzled. 1024 chunks of 8 elems.
    {
        #pragma unroll
        for (int m = 0; m < 4; ++m) {
            const int c = m * 256 + t;
            const int r = c >> 4;
            const int k0 = (c & 15) * 8;
            const float4* s = (const float4*)&in[(row0 + r) * D + k0];
            const float4 x = s[0], y = s[1];
            alignas(16) unsigned short h[8] = {
                f2bf(x.x), f2bf(x.y), f2bf(x.z), f2bf(x.w),
                f2bf(y.x), f2bf(y.y), f2bf(y.z), f2bf(y.w) };
            *(float4*)((char*)Al + ((r * 256 + k0 * 2) ^ ((r & 7) << 4))) =
                *(const float4*)h;
        }
    }
    __syncthreads();

    const int wv   = t >> 6;
    const int lane = t & 63;
    const int rw   = wv * 16;
    const int lrow = lane & 15;
    const int kgrp = lane >> 4;

    f32x4 acc[8];
    #pragma unroll
    for (int n = 0; n < 8; ++n) acc[n] = (f32x4){0.f, 0.f, 0.f, 0.f};

    #pragma unroll
    for (int ks = 0; ks < 4; ++ks) {
        const int arow = rw + lrow;
        const bf16x8 a = *(const bf16x8*)((const char*)Al +
            ((arow * 256 + ks * 64 + kgrp * 16) ^ ((arow & 7) << 4)));
        #pragma unroll
        for (int n = 0; n < 8; ++n) {
            const int brow = n * 16 + lrow;
            const bf16x8 b = *(const bf16x8*)((const char*)Wl +
                ((brow * 256 + ks * 64 + kgrp * 16) ^ ((brow & 7) << 4)));
            acc[n] = __builtin_amdgcn_mfma_f32_16x16x32_bf16(a, b, acc[n], 0, 0, 0);
        }
    }

    // epilogue: acc -> LDS (bf16, swizzled), then coalesced contiguous store.
    // C/D layout: col = lane&15, row = (lane>>4)*4 + i   [guide §3, m89]
    __syncthreads();
    #pragma unroll
    for (int n = 0; n < 8; ++n) {
        const float bv = bias[n * 16 + lrow];
        #pragma unroll
        for (int i = 0; i < 4; ++i) {
            const int r = rw + kgrp * 4 + i;
            const int cb = (r * 256 + (n * 16 + lrow) * 2) ^ ((r & 7) << 4);
            *(unsigned short*)((char*)Al + cb) = f2bf(acc[n][i] + bv);
        }
    }
    __syncthreads();
    {
        float4* dst = (float4*)(outbf + row0 * D);
        #pragma unroll
        for (int m = 0; m < 4; ++m) {
            const int c = m * 256 + t;
            const int r = c >> 4;
            dst[c] = *(const float4*)((const char*)Al + ((c * 16) ^ ((r & 7) << 4)));
        }
    }
}

// ---------------------------------------------------------------------------
// fp32 32-row x 128-col GEMM for the small (8192-row) matmuls.
// mode 0: out = acc ; mode 1: out = add + lrelu(acc)
// ---------------------------------------------------------------------------
__global__ __launch_bounds__(256) void gemm128(
    const float* __restrict__ in, const float* __restrict__ W,
    const float* __restrict__ bias, const float* __restrict__ add,
    float* __restrict__ out, int mode)
{
    __shared__ float Wl[128 * 128];
    __shared__ float inl[32 * 128];
    const int t = threadIdx.x;

    {
        const float4* W4 = (const float4*)W;
        float4* Wl4 = (float4*)Wl;
        #pragma unroll
        for (int m = 0; m < 16; ++m) Wl4[t + m * 256] = W4[t + m * 256];
    }
    const size_t row0 = (size_t)blockIdx.x * 32;
    {
        const float4* in4 = (const float4*)(in + row0 * D);
        float4* inl4 = (float4*)inl;
        #pragma unroll
        for (int m = 0; m < 4; ++m) inl4[t + m * 256] = in4[t + m * 256];
    }
    __syncthreads();

    const int c0 = (t & 31) * 4;
    const int r0 = (t >> 5) * 4;

    float acc[4][4];
    {
        float4 bv = *(const float4*)&bias[c0];
        #pragma unroll
        for (int i = 0; i < 4; ++i) {
            acc[i][0] = bv.x; acc[i][1] = bv.y; acc[i][2] = bv.z; acc[i][3] = bv.w;
        }
    }

    for (int k = 0; k < 128; k += 4) {
        float4 a[4], w[4];
        #pragma unroll
        for (int i = 0; i < 4; ++i) a[i] = *(const float4*)&inl[(r0 + i) * D + k];
        #pragma unroll
        for (int kk = 0; kk < 4; ++kk) w[kk] = *(const float4*)&Wl[(k + kk) * D + c0];
        #pragma unroll
        for (int i = 0; i < 4; ++i) {
            const float* ai = (const float*)&a[i];
            #pragma unroll
            for (int kk = 0; kk < 4; ++kk) {
                acc[i][0] = fmaf(ai[kk], w[kk].x, acc[i][0]);
                acc[i][1] = fmaf(ai[kk], w[kk].y, acc[i][1]);
                acc[i][2] = fmaf(ai[kk], w[kk].z, acc[i][2]);
                acc[i][3] = fmaf(ai[kk], w[kk].w, acc[i][3]);
            }
        }
    }

    #pragma unroll
    for (int i = 0; i < 4; ++i) {
        const size_t r = row0 + r0 + i;
        float4 o = make_float4(acc[i][0], acc[i][1], acc[i][2], acc[i][3]);
        if (mode == 1) {
            float4 ad = *(const float4*)&add[r * D + c0];
            o.x = ad.x + (o.x >= 0.f ? o.x : 0.2f * o.x);
            o.y = ad.y + (o.y >= 0.f ? o.y : 0.2f * o.y);
            o.z = ad.z + (o.z >= 0.f ? o.z : 0.2f * o.z);
            o.w = ad.w + (o.w >= 0.f ? o.w : 0.2f * o.w);
        }
        *(float4*)&out[r * D + c0] = o;
    }
}

// ---------------------------------------------------------------------------
// h0[j][b][:] = bn(entity_embs[idx_j[b]])
// ---------------------------------------------------------------------------
__global__ __launch_bounds__(256) void bn_gather(
    const int* __restrict__ i_idx, const int* __restrict__ u_idx,
    const float* __restrict__ embs,
    const float* __restrict__ gamma, const float* __restrict__ beta,
    const float* __restrict__ mean,  const float* __restrict__ var,
    float* __restrict__ h0)
{
    const int tid = blockIdx.x * 256 + threadIdx.x;
    const int d4 = tid & 31;
    const int b  = (tid >> 5) & (B - 1);
    const int j  = tid >> 17;
    const int idx = j ? u_idx[b] : i_idx[b];

    const int d0 = d4 * 4;
    float4 x = *(const float4*)&embs[(size_t)idx * D + d0];
    float4 m = *(const float4*)&mean[d0];
    float4 v = *(const float4*)&var[d0];
    float4 g = *(const float4*)&gamma[d0];
    float4 bt = *(const float4*)&beta[d0];

    float4 o;
    o.x = (x.x - m.x) * g.x * rsqrtf(v.x + EPS) + bt.x;
    o.y = (x.y - m.y) * g.y * rsqrtf(v.y + EPS) + bt.y;
    o.z = (x.z - m.z) * g.z * rsqrtf(v.z + EPS) + bt.z;
    o.w = (x.w - m.w) * g.w * rsqrtf(v.w + EPS) + bt.w;

    *(float4*)&h0[(size_t)tid * 4] = o;
}

// ---------------------------------------------------------------------------
// Per (j,b): 32x128 tanh table, FM over K=64 neighbors (Etr now bf16),
// g = h0 + (s*s - sum(v*v))
// ---------------------------------------------------------------------------
__global__ __launch_bounds__(256) void aggregate(
    const int* __restrict__ i_idx, const int* __restrict__ u_idx,
    const int* __restrict__ adj_e, const int* __restrict__ adj_r,
    const unsigned short* __restrict__ Etr, const float* __restrict__ rel_embs,
    const float* __restrict__ hW,  const float* __restrict__ h0,
    float* __restrict__ g_out)
{
    __shared__ float hw_s[D];
    __shared__ float tt[NREL * D];
    __shared__ int ents[KNB];
    __shared__ int rels[KNB];
    __shared__ float ps[2][D];
    __shared__ float pq[2][D];

    const int t = threadIdx.x;
    const int b = blockIdx.x & (B - 1);
    const int j = blockIdx.x >> 12;
    const size_t rowbase = ((size_t)j * B + b) * D;
    const int idx = j ? u_idx[b] : i_idx[b];

    if (t < D) hw_s[t] = hW[rowbase + t];
    if (t >= 128 && t < 128 + KNB) {
        const int k = t - 128;
        ents[k] = adj_e[(size_t)idx * KNB + k];
        rels[k] = adj_r[(size_t)idx * KNB + k];
    }
    __syncthreads();

    for (int m = t; m < NREL * D; m += 256)
        tt[m] = tanhf(hw_s[m & (D - 1)] + rel_embs[m]);
    __syncthreads();

    const int grp = t >> 7;
    const int d = t & (D - 1);
    float s = 0.f, q = 0.f;
    #pragma unroll 4
    for (int k = grp; k < KNB; k += 2) {
        const float v = bf2f(Etr[(size_t)ents[k] * D + d]) * tt[rels[k] * D + d];
        s += v;
        q = fmaf(v, v, q);
    }
    ps[grp][d] = s;
    pq[grp][d] = q;
    __syncthreads();

    if (t < D) {
        const float ss = ps[0][t] + ps[1][t];
        const float qq = pq[0][t] + pq[1][t];
        g_out[rowbase + t] = h0[rowbase + t] + ss * ss - qq;
    }
}

// ---------------------------------------------------------------------------
// out[b] = u_e[b]·wl[0:128] + h[b]·wl[128:256] + wl_b
// ---------------------------------------------------------------------------
__global__ __launch_bounds__(256) void final_dot(
    const float* __restrict__ hfin, const float* __restrict__ wl_w,
    const float* __restrict__ wl_b, float* __restrict__ out)
{
    const int t = threadIdx.x;
    const int w = t >> 6;
    const int lane = t & 63;
    const int b = blockIdx.x * 4 + w;

    const float* hu = hfin + ((size_t)B + b) * D;
    const float* hh = hfin + (size_t)b * D;

    float v = hu[lane]      * wl_w[lane]
            + hu[lane + 64] * wl_w[lane + 64]
            + hh[lane]      * wl_w[128 + lane]
            + hh[lane + 64] * wl_w[192 + lane];
    #pragma unroll
    for (int off = 32; off; off >>= 1) v += __shfl_xor(v, off);
    if (lane == 0) out[b] = v + wl_b[0];
}

extern "C" void kernel_launch(void* const* d_in, const int* in_sizes, int n_in,
                              void* d_out, int out_size, void* d_ws, size_t ws_size,
                              hipStream_t stream) {
    const int*   u        = (const int*)d_in[0];
    const int*   ii       = (const int*)d_in[1];
    const int*   adj_e    = (const int*)d_in[2];
    const int*   adj_r    = (const int*)d_in[3];
    const float* embs     = (const float*)d_in[4];
    const float* rel_embs = (const float*)d_in[5];
    const float* gamma    = (const float*)d_in[6];
    const float* beta     = (const float*)d_in[7];
    const float* mean     = (const float*)d_in[8];
    const float* var      = (const float*)d_in[9];
    const float* Wr1_w    = (const float*)d_in[10];
    const float* Wr1_b    = (const float*)d_in[11];
    const float* W1_w     = (const float*)d_in[12];
    const float* W1_b     = (const float*)d_in[13];
    const float* wl_w     = (const float*)d_in[14];
    const float* wl_b     = (const float*)d_in[15];
    float* out = (float*)d_out;

    const int n_ent = in_sizes[2] / KNB;    // 200000

    char* p = (char*)d_ws;
    unsigned short* Etr = (unsigned short*)p;           p += (size_t)n_ent * D * 2;   // 51.2 MB
    unsigned short* Wt  = (unsigned short*)p;           p += (size_t)D * D * 2;       // 32 KB
    float* h0   = (float*)p;                            p += (size_t)2 * B * D * 4;
    float* hWb  = (float*)p;                            p += (size_t)2 * B * D * 4;
    float* gb   = (float*)p;                            p += (size_t)2 * B * D * 4;
    float* hfin = (float*)p;

    // 1. Wt = bf16(Wr1_w^T)
    wt_prep<<<1, 256, 0, stream>>>(Wr1_w, Wt);
    // 2. h0 = bn(entity_embs[{i,u}])   (independent of 1)
    bn_gather<<<(2 * B * 32) / 256, 256, 0, stream>>>(ii, u, embs, gamma, beta, mean, var, h0);
    // 3. Etr = bf16(embs @ Wr1 + b)    (MFMA)
    gemm_etr<<<n_ent / 64, 256, 0, stream>>>(embs, Wt, Wr1_b, Etr);
    // 4. hW = h0 @ Wr1 + b             (fp32, small)
    gemm128<<<(2 * B) / 32, 256, 0, stream>>>(h0, Wr1_w, Wr1_b, nullptr, hWb, 0);
    // 5. FM aggregation -> g = h0 + Nh
    aggregate<<<2 * B, 256, 0, stream>>>(ii, u, adj_e, adj_r, Etr, rel_embs, hWb, h0, gb);
    // 6. hfin = h0 + lrelu(g @ W1 + b)
    gemm128<<<(2 * B) / 32, 256, 0, stream>>>(gb, W1_w, W1_b, h0, hfin, 1);
    // 7. out = [u_e, h] @ wl + b
    final_dot<<<B / 4, 256, 0, stream>>>(hfin, wl_w, wl_b, out);
}

// Round 3
// 95.273 us; speedup vs baseline: 1.8997x; 1.2427x over previous
//
#include <hip/hip_runtime.h>

#define B     4096
#define KNB   64
#define D     128
#define NREL  32
#define EPS   1e-5f

typedef __attribute__((ext_vector_type(8))) short bf16x8;
typedef __attribute__((ext_vector_type(4))) float f32x4;

__device__ inline unsigned short f2bf(float f) {
    unsigned u = __float_as_uint(f);
    return (unsigned short)((u + 0x7FFFu + ((u >> 16) & 1u)) >> 16);
}
__device__ inline float bfu_lo(unsigned u) { return __uint_as_float(u << 16); }
__device__ inline float bfu_hi(unsigned u) { return __uint_as_float(u & 0xFFFF0000u); }

// tanh(x) = 1 - 2/(exp(2x)+1), exp via native v_exp_f32. |err| ~1e-6.
// Saturates correctly: x>>0 -> e=inf -> 1 ; x<<0 -> e=0 -> -1.
__device__ inline float fast_tanh(float x) {
    float e = __builtin_amdgcn_exp2f(x * 2.885390082f);   // 2*log2(e)
    return 1.f - 2.f * __builtin_amdgcn_rcpf(e + 1.f);
}

// ---------------------------------------------------------------------------
// Wt[n][k] = bf16(W[k][n]) — one small block, runs once per launch
// ---------------------------------------------------------------------------
__global__ __launch_bounds__(256) void wt_prep(
    const float* __restrict__ W, unsigned short* __restrict__ Wt)
{
    const int t = threadIdx.x;
    #pragma unroll
    for (int m = 0; m < 64; ++m) {
        const int idx = m * 256 + t;
        const int k = idx >> 7, n = idx & 127;
        Wt[n * D + k] = f2bf(W[idx]);
    }
}

// ---------------------------------------------------------------------------
// Etr = bf16( in(f32) @ W + bias ), via 16x16x32 bf16 MFMA.
// Block: 256 thr (4 waves), tile 64 rows x 128 cols; XOR-swizzled LDS.
// ---------------------------------------------------------------------------
__global__ __launch_bounds__(256) void gemm_etr(
    const float* __restrict__ in, const unsigned short* __restrict__ Wt,
    const float* __restrict__ bias, unsigned short* __restrict__ outbf)
{
    __shared__ unsigned short Al[64 * 128];    // 16 KB
    __shared__ unsigned short Wl[128 * 128];   // 32 KB

    const int t = threadIdx.x;
    const size_t row0 = (size_t)blockIdx.x * 64;

    {
        const float4* src = (const float4*)Wt;
        #pragma unroll
        for (int m = 0; m < 8; ++m) {
            const int c = m * 256 + t;
            const int n = c >> 4;
            float4 v = src[c];
            *(float4*)((char*)Wl + ((c * 16) ^ ((n & 7) << 4))) = v;
        }
    }
    {
        #pragma unroll
        for (int m = 0; m < 4; ++m) {
            const int c = m * 256 + t;
            const int r = c >> 4;
            const int k0 = (c & 15) * 8;
            const float4* s = (const float4*)&in[(row0 + r) * D + k0];
            const float4 x = s[0], y = s[1];
            alignas(16) unsigned short h[8] = {
                f2bf(x.x), f2bf(x.y), f2bf(x.z), f2bf(x.w),
                f2bf(y.x), f2bf(y.y), f2bf(y.z), f2bf(y.w) };
            *(float4*)((char*)Al + ((r * 256 + k0 * 2) ^ ((r & 7) << 4))) =
                *(const float4*)h;
        }
    }
    __syncthreads();

    const int wv   = t >> 6;
    const int lane = t & 63;
    const int rw   = wv * 16;
    const int lrow = lane & 15;
    const int kgrp = lane >> 4;

    f32x4 acc[8];
    #pragma unroll
    for (int n = 0; n < 8; ++n) acc[n] = (f32x4){0.f, 0.f, 0.f, 0.f};

    #pragma unroll
    for (int ks = 0; ks < 4; ++ks) {
        const int arow = rw + lrow;
        const bf16x8 a = *(const bf16x8*)((const char*)Al +
            ((arow * 256 + ks * 64 + kgrp * 16) ^ ((arow & 7) << 4)));
        #pragma unroll
        for (int n = 0; n < 8; ++n) {
            const int brow = n * 16 + lrow;
            const bf16x8 b = *(const bf16x8*)((const char*)Wl +
                ((brow * 256 + ks * 64 + kgrp * 16) ^ ((brow & 7) << 4)));
            acc[n] = __builtin_amdgcn_mfma_f32_16x16x32_bf16(a, b, acc[n], 0, 0, 0);
        }
    }

    __syncthreads();
    #pragma unroll
    for (int n = 0; n < 8; ++n) {
        const float bv = bias[n * 16 + lrow];
        #pragma unroll
        for (int i = 0; i < 4; ++i) {
            const int r = rw + kgrp * 4 + i;
            const int cb = (r * 256 + (n * 16 + lrow) * 2) ^ ((r & 7) << 4);
            *(unsigned short*)((char*)Al + cb) = f2bf(acc[n][i] + bv);
        }
    }
    __syncthreads();
    {
        float4* dst = (float4*)(outbf + row0 * D);
        #pragma unroll
        for (int m = 0; m < 4; ++m) {
            const int c = m * 256 + t;
            const int r = c >> 4;
            dst[c] = *(const float4*)((const char*)Al + ((c * 16) ^ ((r & 7) << 4)));
        }
    }
}

// ---------------------------------------------------------------------------
// fp32 32-row x 128-col GEMM for the small (8192-row) matmuls.
// ---------------------------------------------------------------------------
__global__ __launch_bounds__(256) void gemm128(
    const float* __restrict__ in, const float* __restrict__ W,
    const float* __restrict__ bias, const float* __restrict__ add,
    float* __restrict__ out, int mode)
{
    __shared__ float Wl[128 * 128];
    __shared__ float inl[32 * 128];
    const int t = threadIdx.x;

    {
        const float4* W4 = (const float4*)W;
        float4* Wl4 = (float4*)Wl;
        #pragma unroll
        for (int m = 0; m < 16; ++m) Wl4[t + m * 256] = W4[t + m * 256];
    }
    const size_t row0 = (size_t)blockIdx.x * 32;
    {
        const float4* in4 = (const float4*)(in + row0 * D);
        float4* inl4 = (float4*)inl;
        #pragma unroll
        for (int m = 0; m < 4; ++m) inl4[t + m * 256] = in4[t + m * 256];
    }
    __syncthreads();

    const int c0 = (t & 31) * 4;
    const int r0 = (t >> 5) * 4;

    float acc[4][4];
    {
        float4 bv = *(const float4*)&bias[c0];
        #pragma unroll
        for (int i = 0; i < 4; ++i) {
            acc[i][0] = bv.x; acc[i][1] = bv.y; acc[i][2] = bv.z; acc[i][3] = bv.w;
        }
    }

    for (int k = 0; k < 128; k += 4) {
        float4 a[4], w[4];
        #pragma unroll
        for (int i = 0; i < 4; ++i) a[i] = *(const float4*)&inl[(r0 + i) * D + k];
        #pragma unroll
        for (int kk = 0; kk < 4; ++kk) w[kk] = *(const float4*)&Wl[(k + kk) * D + c0];
        #pragma unroll
        for (int i = 0; i < 4; ++i) {
            const float* ai = (const float*)&a[i];
            #pragma unroll
            for (int kk = 0; kk < 4; ++kk) {
                acc[i][0] = fmaf(ai[kk], w[kk].x, acc[i][0]);
                acc[i][1] = fmaf(ai[kk], w[kk].y, acc[i][1]);
                acc[i][2] = fmaf(ai[kk], w[kk].z, acc[i][2]);
                acc[i][3] = fmaf(ai[kk], w[kk].w, acc[i][3]);
            }
        }
    }

    #pragma unroll
    for (int i = 0; i < 4; ++i) {
        const size_t r = row0 + r0 + i;
        float4 o = make_float4(acc[i][0], acc[i][1], acc[i][2], acc[i][3]);
        if (mode == 1) {
            float4 ad = *(const float4*)&add[r * D + c0];
            o.x = ad.x + (o.x >= 0.f ? o.x : 0.2f * o.x);
            o.y = ad.y + (o.y >= 0.f ? o.y : 0.2f * o.y);
            o.z = ad.z + (o.z >= 0.f ? o.z : 0.2f * o.z);
            o.w = ad.w + (o.w >= 0.f ? o.w : 0.2f * o.w);
        }
        *(float4*)&out[r * D + c0] = o;
    }
}

// ---------------------------------------------------------------------------
// h0[j][b][:] = bn(entity_embs[idx_j[b]])
// ---------------------------------------------------------------------------
__global__ __launch_bounds__(256) void bn_gather(
    const int* __restrict__ i_idx, const int* __restrict__ u_idx,
    const float* __restrict__ embs,
    const float* __restrict__ gamma, const float* __restrict__ beta,
    const float* __restrict__ mean,  const float* __restrict__ var,
    float* __restrict__ h0)
{
    const int tid = blockIdx.x * 256 + threadIdx.x;
    const int d4 = tid & 31;
    const int b  = (tid >> 5) & (B - 1);
    const int j  = tid >> 17;
    const int idx = j ? u_idx[b] : i_idx[b];

    const int d0 = d4 * 4;
    float4 x = *(const float4*)&embs[(size_t)idx * D + d0];
    float4 m = *(const float4*)&mean[d0];
    float4 v = *(const float4*)&var[d0];
    float4 g = *(const float4*)&gamma[d0];
    float4 bt = *(const float4*)&beta[d0];

    float4 o;
    o.x = (x.x - m.x) * g.x * rsqrtf(v.x + EPS) + bt.x;
    o.y = (x.y - m.y) * g.y * rsqrtf(v.y + EPS) + bt.y;
    o.z = (x.z - m.z) * g.z * rsqrtf(v.z + EPS) + bt.z;
    o.w = (x.w - m.w) * g.w * rsqrtf(v.w + EPS) + bt.w;

    *(float4*)&h0[(size_t)tid * 4] = o;
}

// ---------------------------------------------------------------------------
// Per (j,b): 32x128 fast-tanh table, FM over K=64 neighbors (Etr bf16),
// g = h0 + (s*s - sum(v*v)).  4 dims/thread, 8 K-groups, fully unrolled.
// ---------------------------------------------------------------------------
__global__ __launch_bounds__(256) void aggregate(
    const int* __restrict__ i_idx, const int* __restrict__ u_idx,
    const int* __restrict__ adj_e, const int* __restrict__ adj_r,
    const unsigned short* __restrict__ Etr, const float* __restrict__ rel_embs,
    const float* __restrict__ hW,  const float* __restrict__ h0,
    float* __restrict__ g_out)
{
    __shared__ float hw_s[D];
    __shared__ float tt[NREL * D];    // 16 KB
    __shared__ int ents[KNB];         // byte offsets into Etr
    __shared__ int rels[KNB];         // byte offsets into tt
    __shared__ float ps[8][D];        // 4 KB
    __shared__ float pq[8][D];        // 4 KB

    const int t = threadIdx.x;
    const int b = blockIdx.x & (B - 1);
    const int j = blockIdx.x >> 12;
    const size_t rowbase = ((size_t)j * B + b) * D;
    const int idx = j ? u_idx[b] : i_idx[b];

    if (t < D) hw_s[t] = hW[rowbase + t];
    if (t >= D && t < D + KNB) {
        const int k = t - D;
        ents[k] = adj_e[(size_t)idx * KNB + k] * (D * 2);   // row byte offset (bf16)
        rels[k] = adj_r[(size_t)idx * KNB + k] * (D * 4);   // row byte offset (f32)
    }
    __syncthreads();

    // tanh table: 1024 float4, 4 per thread
    {
        const float4* re4 = (const float4*)rel_embs;
        #pragma unroll
        for (int m4 = t; m4 < NREL * D / 4; m4 += 256) {
            const float4 r = re4[m4];
            const float4 hv = *(const float4*)&hw_s[(m4 & 31) * 4];
            float4 o;
            o.x = fast_tanh(hv.x + r.x);
            o.y = fast_tanh(hv.y + r.y);
            o.z = fast_tanh(hv.z + r.z);
            o.w = fast_tanh(hv.w + r.w);
            *(float4*)&tt[m4 * 4] = o;
        }
    }
    __syncthreads();

    const int dq  = t & 31;       // 4-dim group: dims 4*dq .. 4*dq+3
    const int grp = t >> 5;       // 0..7, K-slice
    const char* Eb = (const char*)Etr + dq * 8;
    const char* tb = (const char*)tt  + dq * 16;

    float s0 = 0.f, s1 = 0.f, s2 = 0.f, s3 = 0.f;
    float q0 = 0.f, q1 = 0.f, q2 = 0.f, q3 = 0.f;
    #pragma unroll
    for (int it = 0; it < 8; ++it) {
        const int k = grp + it * 8;
        const uint2  ev = *(const uint2*)(Eb + ents[k]);
        const float4 tv = *(const float4*)(tb + rels[k]);
        const float v0 = bfu_lo(ev.x) * tv.x;
        const float v1 = bfu_hi(ev.x) * tv.y;
        const float v2 = bfu_lo(ev.y) * tv.z;
        const float v3 = bfu_hi(ev.y) * tv.w;
        s0 += v0; s1 += v1; s2 += v2; s3 += v3;
        q0 = fmaf(v0, v0, q0); q1 = fmaf(v1, v1, q1);
        q2 = fmaf(v2, v2, q2); q3 = fmaf(v3, v3, q3);
    }
    *(float4*)&ps[grp][dq * 4] = make_float4(s0, s1, s2, s3);
    *(float4*)&pq[grp][dq * 4] = make_float4(q0, q1, q2, q3);
    __syncthreads();

    if (t < D) {
        float ss = 0.f, qq = 0.f;
        #pragma unroll
        for (int g = 0; g < 8; ++g) { ss += ps[g][t]; qq += pq[g][t]; }
        g_out[rowbase + t] = h0[rowbase + t] + ss * ss - qq;
    }
}

// ---------------------------------------------------------------------------
// out[b] = u_e[b]·wl[0:128] + h[b]·wl[128:256] + wl_b
// ---------------------------------------------------------------------------
__global__ __launch_bounds__(256) void final_dot(
    const float* __restrict__ hfin, const float* __restrict__ wl_w,
    const float* __restrict__ wl_b, float* __restrict__ out)
{
    const int t = threadIdx.x;
    const int w = t >> 6;
    const int lane = t & 63;
    const int b = blockIdx.x * 4 + w;

    const float* hu = hfin + ((size_t)B + b) * D;
    const float* hh = hfin + (size_t)b * D;

    float v = hu[lane]      * wl_w[lane]
            + hu[lane + 64] * wl_w[lane + 64]
            + hh[lane]      * wl_w[128 + lane]
            + hh[lane + 64] * wl_w[192 + lane];
    #pragma unroll
    for (int off = 32; off; off >>= 1) v += __shfl_xor(v, off);
    if (lane == 0) out[b] = v + wl_b[0];
}

extern "C" void kernel_launch(void* const* d_in, const int* in_sizes, int n_in,
                              void* d_out, int out_size, void* d_ws, size_t ws_size,
                              hipStream_t stream) {
    const int*   u        = (const int*)d_in[0];
    const int*   ii       = (const int*)d_in[1];
    const int*   adj_e    = (const int*)d_in[2];
    const int*   adj_r    = (const int*)d_in[3];
    const float* embs     = (const float*)d_in[4];
    const float* rel_embs = (const float*)d_in[5];
    const float* gamma    = (const float*)d_in[6];
    const float* beta     = (const float*)d_in[7];
    const float* mean     = (const float*)d_in[8];
    const float* var      = (const float*)d_in[9];
    const float* Wr1_w    = (const float*)d_in[10];
    const float* Wr1_b    = (const float*)d_in[11];
    const float* W1_w     = (const float*)d_in[12];
    const float* W1_b     = (const float*)d_in[13];
    const float* wl_w     = (const float*)d_in[14];
    const float* wl_b     = (const float*)d_in[15];
    float* out = (float*)d_out;

    const int n_ent = in_sizes[2] / KNB;    // 200000

    char* p = (char*)d_ws;
    unsigned short* Etr = (unsigned short*)p;           p += (size_t)n_ent * D * 2;   // 51.2 MB
    unsigned short* Wt  = (unsigned short*)p;           p += (size_t)D * D * 2;       // 32 KB
    float* h0   = (float*)p;                            p += (size_t)2 * B * D * 4;
    float* hWb  = (float*)p;                            p += (size_t)2 * B * D * 4;
    float* gb   = (float*)p;                            p += (size_t)2 * B * D * 4;
    float* hfin = (float*)p;

    // 1. Wt = bf16(Wr1_w^T)
    wt_prep<<<1, 256, 0, stream>>>(Wr1_w, Wt);
    // 2. h0 = bn(entity_embs[{i,u}])
    bn_gather<<<(2 * B * 32) / 256, 256, 0, stream>>>(ii, u, embs, gamma, beta, mean, var, h0);
    // 3. Etr = bf16(embs @ Wr1 + b)    (MFMA)
    gemm_etr<<<n_ent / 64, 256, 0, stream>>>(embs, Wt, Wr1_b, Etr);
    // 4. hW = h0 @ Wr1 + b             (fp32, small)
    gemm128<<<(2 * B) / 32, 256, 0, stream>>>(h0, Wr1_w, Wr1_b, nullptr, hWb, 0);
    // 5. FM aggregation -> g = h0 + Nh
    aggregate<<<2 * B, 256, 0, stream>>>(ii, u, adj_e, adj_r, Etr, rel_embs, hWb, h0, gb);
    // 6. hfin = h0 + lrelu(g @ W1 + b)
    gemm128<<<(2 * B) / 32, 256, 0, stream>>>(gb, W1_w, W1_b, h0, hfin, 1);
    // 7. out = [u_e, h] @ wl + b
    final_dot<<<B / 4, 256, 0, stream>>>(hfin, wl_w, wl_b, out);
}